// Round 1
// baseline (242.130 us; speedup 1.0000x reference)
//
#include <hip/hip_runtime.h>
#include <math.h>

#define NB   8
#define NC   1024
#define NL   4096
#define NCTX 768
#define NG   8
#define CPG  128          // channels per group
#define EPSV 1e-5f
#define SCALEV 0.03125f   // 1024^-0.5

// workspace layout (float offsets)
enum : int {
  OFF_CTXN  = 0,                          // 8*768   = 6144
  OFF_KV    = OFF_CTXN + NB*NCTX,         // 8*2048  = 16384
  OFF_WC    = OFF_KV   + NB*2048,         // 8*1024  (wcoef = gamma*kq)
  OFF_PV    = OFF_WC   + NB*NC,           // 8*1024
  OFF_SPART = OFF_PV   + NB*NC,           // 8*8*16*2 = 2048
  OFF_TPART = OFF_SPART+ NB*NG*16*2,      // 8*8*4*4096 = 1048576
  OFF_ATTN  = OFF_TPART+ NB*NG*4*NL,      // 8*4096
  WS_FLOATS = OFF_ATTN + NB*NL
};

__device__ __forceinline__ float breduce_sum(float v, float* red) {
  int t = threadIdx.x;
  red[t] = v; __syncthreads();
  for (int s = 128; s > 0; s >>= 1) { if (t < s) red[t] += red[t + s]; __syncthreads(); }
  float r = red[0]; __syncthreads();
  return r;
}
__device__ __forceinline__ float breduce_max(float v, float* red) {
  int t = threadIdx.x;
  red[t] = v; __syncthreads();
  for (int s = 128; s > 0; s >>= 1) { if (t < s) red[t] = fmaxf(red[t], red[t + s]); __syncthreads(); }
  float r = red[0]; __syncthreads();
  return r;
}

// ---------------- K1: LayerNorm(context) -> ctxn ----------------
__global__ void k_ln(const float* __restrict__ ctx, const float* __restrict__ lng,
                     const float* __restrict__ lnb, float* __restrict__ ws) {
  __shared__ float red[256];
  int b = blockIdx.x, t = threadIdx.x;
  const float* row = ctx + b * NCTX;
  float v0 = row[t], v1 = row[t + 256], v2 = row[t + 512];
  float mu = breduce_sum(v0 + v1 + v2, red) * (1.0f / NCTX);
  float d0 = v0 - mu, d1 = v1 - mu, d2 = v2 - mu;
  float var = breduce_sum(d0*d0 + d1*d1 + d2*d2, red) * (1.0f / NCTX);
  float rstd = rsqrtf(var + EPSV);
  float* o = ws + OFF_CTXN + b * NCTX;
  o[t]       = d0 * rstd * lng[t]       + lnb[t];
  o[t + 256] = d1 * rstd * lng[t + 256] + lnb[t + 256];
  o[t + 512] = d2 * rstd * lng[t + 512] + lnb[t + 512];
}

// ---------------- K2: kv = ctxn @ Wkv^T + bkv ----------------
__global__ void k_kv(const float* __restrict__ Wkv, const float* __restrict__ bkv,
                     float* __restrict__ ws) {
  __shared__ float sc[NCTX];
  int b = blockIdx.y, t = threadIdx.x;
  int j = blockIdx.x * 256 + t;
  const float* cn = ws + OFF_CTXN + b * NCTX;
  for (int i = t; i < NCTX; i += 256) sc[i] = cn[i];
  __syncthreads();
  const float* wrow = Wkv + (size_t)j * NCTX;
  float acc = 0.f;
  #pragma unroll 8
  for (int i = 0; i < NCTX; i++) acc = fmaf(sc[i], wrow[i], acc);
  ws[OFF_KV + b * 2048 + j] = acc + bkv[j];
}

// ---------------- K3: wcoef = gamma * (k @ Wq), pv = Wp @ v ----------------
__global__ void k_wcpv(const float* __restrict__ Wq, const float* __restrict__ Wp,
                       const float* __restrict__ gng, float* __restrict__ ws) {
  __shared__ float sk[NC];
  __shared__ float sv[NC];
  int b = blockIdx.y, t = threadIdx.x;
  int c = blockIdx.x * 256 + t;
  const float* kv = ws + OFF_KV + b * 2048;
  for (int i = t; i < NC; i += 256) { sk[i] = kv[i]; sv[i] = kv[NC + i]; }
  __syncthreads();
  // kq[b,c] = sum_o k[o] * Wq[o,c]  (coalesced in c)
  float acc = 0.f;
  #pragma unroll 8
  for (int o = 0; o < NC; o++) acc = fmaf(sk[o], Wq[(size_t)o * NC + c], acc);
  ws[OFF_WC + b * NC + c] = gng[c] * acc;
  // pv[b,o] = sum_c2 v[c2] * Wp[o,c2]   (o == c index here)
  const float* wrow = Wp + (size_t)c * NC;
  float acc2 = 0.f;
  #pragma unroll 8
  for (int i = 0; i < NC; i++) acc2 = fmaf(sv[i], wrow[i], acc2);
  ws[OFF_PV + b * NC + c] = acc2;
}

// ---------------- K4: one pass over x: GN stat partials + score partial dots ----------------
// grid (lc=4, cs=4, b*g=64), block 256. Each block: 32 channels x 1024 l's.
__global__ void k_pass1(const float* __restrict__ x, float* __restrict__ ws) {
  __shared__ float red[256];
  int t  = threadIdx.x;
  int lc = blockIdx.x;          // l chunk 0..3
  int cs = blockIdx.y;          // channel split 0..3
  int bz = blockIdx.z;          // b*8+g
  int b = bz >> 3, g = bz & 7;
  int c0 = g * CPG + cs * 32;
  int l4 = lc * 256 + t;        // float4 index within a 4096 row
  const float4* x4 = reinterpret_cast<const float4*>(x);
  const float* wc = ws + OFF_WC + b * NC;
  float4 tacc = make_float4(0.f, 0.f, 0.f, 0.f);
  float s1 = 0.f, s2 = 0.f;
  #pragma unroll 4
  for (int ci = 0; ci < 32; ci++) {
    int c = c0 + ci;
    float w = wc[c];
    float4 v = x4[(size_t)(b * NC + c) * 1024 + l4];
    tacc.x = fmaf(w, v.x, tacc.x);
    tacc.y = fmaf(w, v.y, tacc.y);
    tacc.z = fmaf(w, v.z, tacc.z);
    tacc.w = fmaf(w, v.w, tacc.w);
    s1 += (v.x + v.y) + (v.z + v.w);
    s2 = fmaf(v.x, v.x, s2); s2 = fmaf(v.y, v.y, s2);
    s2 = fmaf(v.z, v.z, s2); s2 = fmaf(v.w, v.w, s2);
  }
  float4* tp4 = reinterpret_cast<float4*>(ws + OFF_TPART) + (size_t)((b * NG + g) * 4 + cs) * 1024;
  tp4[l4] = tacc;
  float S1 = breduce_sum(s1, red);
  float S2 = breduce_sum(s2, red);
  if (t == 0) {
    float* sp = ws + OFF_SPART + ((b * NG + g) * 16 + cs * 4 + lc) * 2;
    sp[0] = S1; sp[1] = S2;
  }
}

// ---------------- K5: per-b combine + softmax -> attn ----------------
__global__ void k_softmax(float* __restrict__ ws) {
  __shared__ float red[256];
  __shared__ float srstd[NG];
  int b = blockIdx.x, t = threadIdx.x;
  if (t < NG) {
    const float* sp = ws + OFF_SPART + (b * NG + t) * 32;
    float S1 = 0.f, S2 = 0.f;
    #pragma unroll
    for (int i = 0; i < 16; i++) { S1 += sp[i * 2]; S2 += sp[i * 2 + 1]; }
    const float invN = 1.0f / ((float)CPG * (float)NL);
    float mu = S1 * invN;
    float var = S2 * invN - mu * mu;
    srstd[t] = rsqrtf(var + EPSV);
  }
  __syncthreads();
  float sv[16];
  const float* tp = ws + OFF_TPART + (size_t)b * NG * 4 * NL;
  #pragma unroll
  for (int i = 0; i < 16; i++) {
    int l = t + i * 256;
    float acc = 0.f;
    #pragma unroll
    for (int g = 0; g < NG; g++) {
      const float* tg = tp + (size_t)g * 4 * NL;
      float sum4 = (tg[l] + tg[NL + l]) + (tg[2 * NL + l] + tg[3 * NL + l]);
      acc = fmaf(srstd[g], sum4, acc);
    }
    sv[i] = SCALEV * acc;   // per-b constants cancel under softmax
  }
  float m = sv[0];
  #pragma unroll
  for (int i = 1; i < 16; i++) m = fmaxf(m, sv[i]);
  float M = breduce_max(m, red);
  float s = 0.f;
  #pragma unroll
  for (int i = 0; i < 16; i++) { sv[i] = expf(sv[i] - M); s += sv[i]; }
  float S = breduce_sum(s, red);
  float inv = 1.0f / S;
  float* at = ws + OFF_ATTN + b * NL;
  #pragma unroll
  for (int i = 0; i < 16; i++) at[t + i * 256] = sv[i] * inv;
}

// ---------------- K6: out = x + attn*pv + bp ----------------
__global__ void k_out(const float* __restrict__ x, const float* __restrict__ bp,
                      const float* __restrict__ ws, float* __restrict__ out) {
  const float4* x4 = reinterpret_cast<const float4*>(x);
  float4* o4 = reinterpret_cast<float4*>(out);
  const float4* a4 = reinterpret_cast<const float4*>(ws + OFF_ATTN);
  const float* pv = ws + OFF_PV;
  const size_t NT4 = (size_t)NB * NC * NL / 4;  // 8388608
  for (size_t i = (size_t)blockIdx.x * blockDim.x + threadIdx.x; i < NT4;
       i += (size_t)gridDim.x * blockDim.x) {
    int b  = (int)(i >> 20);
    int c  = (int)((i >> 10) & (NC - 1));
    int l4 = (int)(i & 1023);
    float4 xv = x4[i];
    float4 av = a4[(size_t)b * 1024 + l4];
    float p  = pv[b * NC + c];
    float bb = bp[c];
    float4 r;
    r.x = xv.x + fmaf(av.x, p, bb);
    r.y = xv.y + fmaf(av.y, p, bb);
    r.z = xv.z + fmaf(av.z, p, bb);
    r.w = xv.w + fmaf(av.w, p, bb);
    o4[i] = r;
  }
}

extern "C" void kernel_launch(void* const* d_in, const int* in_sizes, int n_in,
                              void* d_out, int out_size, void* d_ws, size_t ws_size,
                              hipStream_t stream) {
  const float* x    = (const float*)d_in[0];
  const float* ctx  = (const float*)d_in[1];
  const float* gng  = (const float*)d_in[2];
  // d_in[3] = gn_beta, d_in[7] = bq : per-b constants, cancel under softmax
  const float* lng  = (const float*)d_in[4];
  const float* lnb  = (const float*)d_in[5];
  const float* Wq   = (const float*)d_in[6];
  const float* Wkv  = (const float*)d_in[8];
  const float* bkv  = (const float*)d_in[9];
  const float* Wp   = (const float*)d_in[10];
  const float* bp   = (const float*)d_in[11];
  float* ws  = (float*)d_ws;
  float* out = (float*)d_out;

  hipLaunchKernelGGL(k_ln,      dim3(NB),        dim3(256), 0, stream, ctx, lng, lnb, ws);
  hipLaunchKernelGGL(k_kv,      dim3(8, NB),     dim3(256), 0, stream, Wkv, bkv, ws);
  hipLaunchKernelGGL(k_wcpv,    dim3(4, NB),     dim3(256), 0, stream, Wq, Wp, gng, ws);
  hipLaunchKernelGGL(k_pass1,   dim3(4, 4, 64),  dim3(256), 0, stream, x, ws);
  hipLaunchKernelGGL(k_softmax, dim3(NB),        dim3(256), 0, stream, ws);
  hipLaunchKernelGGL(k_out,     dim3(2048),      dim3(256), 0, stream, x, bp, ws, out);
}

// Round 3
// 143.531 us; speedup vs baseline: 1.6870x; 1.6870x over previous
//
#include <hip/hip_runtime.h>
#include <math.h>

#define NB   8
#define NC   1024
#define NL   4096
#define NCTX 768
#define NG   8
#define EPSV 1e-5f
#define SCALEV 0.03125f   // 1024^-0.5

// workspace layout (float offsets)
enum : int {
  OFF_CTXN  = 0,                         // 8*768    = 6144
  OFF_KV    = 6144,                      // 8*2048   = 16384
  OFF_PV    = 22528,                     // 8*1024   = 8192
  OFF_QP    = 30720,                     // 64 chunks * 8 b * 1024 c = 524288
  OFF_SPART = 555008,                    // 8b*8g*(2cs*4lc)*2 = 1024
  OFF_TPART = 556032,                    // 8b*8g*2cs*4096 = 524288
  OFF_ATTN  = 1080320,                   // 8*4096 = 32768
  WS_FLOATS = 1113088                    // ~4.45 MB
};

__device__ __forceinline__ float breduce_sum(float v, float* red) {
  int t = threadIdx.x;
  red[t] = v; __syncthreads();
  for (int s = 128; s > 0; s >>= 1) { if (t < s) red[t] += red[t + s]; __syncthreads(); }
  float r = red[0]; __syncthreads();
  return r;
}
__device__ __forceinline__ float breduce_max(float v, float* red) {
  int t = threadIdx.x;
  red[t] = v; __syncthreads();
  for (int s = 128; s > 0; s >>= 1) { if (t < s) red[t] = fmaxf(red[t], red[t + s]); __syncthreads(); }
  float r = red[0]; __syncthreads();
  return r;
}
__device__ __forceinline__ float wave_sum(float v) {
  #pragma unroll
  for (int off = 32; off > 0; off >>= 1) v += __shfl_xor(v, off, 64);
  return v;
}

// ---------------- K1: LayerNorm(context) -> ctxn ----------------
__global__ void k_ln(const float* __restrict__ ctx, const float* __restrict__ lng,
                     const float* __restrict__ lnb, float* __restrict__ ws) {
  __shared__ float red[256];
  int b = blockIdx.x, t = threadIdx.x;
  const float* row = ctx + b * NCTX;
  float v0 = row[t], v1 = row[t + 256], v2 = row[t + 512];
  float mu = breduce_sum(v0 + v1 + v2, red) * (1.0f / NCTX);
  float d0 = v0 - mu, d1 = v1 - mu, d2 = v2 - mu;
  float var = breduce_sum(d0*d0 + d1*d1 + d2*d2, red) * (1.0f / NCTX);
  float rstd = rsqrtf(var + EPSV);
  float* o = ws + OFF_CTXN + b * NCTX;
  o[t]       = d0 * rstd * lng[t]       + lnb[t];
  o[t + 256] = d1 * rstd * lng[t + 256] + lnb[t + 256];
  o[t + 512] = d2 * rstd * lng[t + 512] + lnb[t + 512];
}

// ---------------- K2: kv = ctxn @ Wkv^T + bkv  (wave-per-row) ----------------
// grid 128, block 256 (4 waves), 16 rows/block, 4 rows/wave.
__global__ void k_kv(const float* __restrict__ Wkv, const float* __restrict__ bkv,
                     float* __restrict__ ws) {
  __shared__ float4 sc4[8 * 192];       // ctxn, all 8 batches (24 KB)
  int t = threadIdx.x, bid = blockIdx.x;
  const float4* cn4 = reinterpret_cast<const float4*>(ws + OFF_CTXN);
  #pragma unroll
  for (int rep = 0; rep < 6; rep++) sc4[rep * 256 + t] = cn4[rep * 256 + t];
  __syncthreads();
  int wave = t >> 6, lane = t & 63;
  const float4* W4 = reinterpret_cast<const float4*>(Wkv);
  #pragma unroll
  for (int rr = 0; rr < 4; rr++) {
    int j = bid * 16 + wave * 4 + rr;
    float4 wv0 = W4[(size_t)j * 192 + lane];
    float4 wv1 = W4[(size_t)j * 192 + lane + 64];
    float4 wv2 = W4[(size_t)j * 192 + lane + 128];
    #pragma unroll
    for (int b = 0; b < 8; b++) {
      const float4* sb = sc4 + b * 192;
      float4 c0 = sb[lane], c1 = sb[lane + 64], c2 = sb[lane + 128];
      float a = wv0.x*c0.x + wv0.y*c0.y + wv0.z*c0.z + wv0.w*c0.w
              + wv1.x*c1.x + wv1.y*c1.y + wv1.z*c1.z + wv1.w*c1.w
              + wv2.x*c2.x + wv2.y*c2.y + wv2.z*c2.z + wv2.w*c2.w;
      a = wave_sum(a);
      if (lane == 0) ws[OFF_KV + b * 2048 + j] = a + bkv[j];
    }
  }
}

// ---------------- K3: kq partials (split-K) + pv (wave-per-row) ----------------
// blocks [0,64): kq chunk oc=bid, o in [oc*16, oc*16+16), full c-width via float4.
// blocks [64,128): pv rows, 16 rows/block.
__global__ void k_mv(const float* __restrict__ Wq, const float* __restrict__ Wp,
                     float* __restrict__ ws) {
  __shared__ float4 sbuf[8 * 256];      // 32 KB, dual-use
  int t = threadIdx.x, bid = blockIdx.x;
  if (bid < 64) {
    float* sk = reinterpret_cast<float*>(sbuf);   // sk[8][16]
    if (t < 128) { int b = t >> 4, o = t & 15; sk[b * 16 + o] = ws[OFF_KV + b * 2048 + bid * 16 + o]; }
    __syncthreads();
    const float4* Wq4 = reinterpret_cast<const float4*>(Wq);
    float4 acc[8];
    #pragma unroll
    for (int b = 0; b < 8; b++) acc[b] = make_float4(0.f, 0.f, 0.f, 0.f);
    int o0 = bid * 16;
    #pragma unroll 4
    for (int oi = 0; oi < 16; oi++) {
      float4 w = Wq4[(size_t)(o0 + oi) * 256 + t];
      #pragma unroll
      for (int b = 0; b < 8; b++) {
        float kk = sk[b * 16 + oi];
        acc[b].x = fmaf(kk, w.x, acc[b].x);
        acc[b].y = fmaf(kk, w.y, acc[b].y);
        acc[b].z = fmaf(kk, w.z, acc[b].z);
        acc[b].w = fmaf(kk, w.w, acc[b].w);
      }
    }
    float4* qp4 = reinterpret_cast<float4*>(ws + OFF_QP);
    #pragma unroll
    for (int b = 0; b < 8; b++) qp4[(bid * 8 + b) * 256 + t] = acc[b];
  } else {
    // load v (all 8 b) into LDS as float4
    const float4* kv4 = reinterpret_cast<const float4*>(ws + OFF_KV);
    #pragma unroll
    for (int rep = 0; rep < 8; rep++) {
      int idx = rep * 256 + t;            // idx < 2048
      int b = idx >> 8, i = idx & 255;
      sbuf[idx] = kv4[b * 512 + 256 + i];
    }
    __syncthreads();
    int wave = t >> 6, lane = t & 63;
    const float4* Wp4 = reinterpret_cast<const float4*>(Wp);
    #pragma unroll
    for (int rr = 0; rr < 4; rr++) {
      int o = (bid - 64) * 16 + wave * 4 + rr;
      float4 wv0 = Wp4[(size_t)o * 256 + lane];
      float4 wv1 = Wp4[(size_t)o * 256 + lane + 64];
      float4 wv2 = Wp4[(size_t)o * 256 + lane + 128];
      float4 wv3 = Wp4[(size_t)o * 256 + lane + 192];
      #pragma unroll
      for (int b = 0; b < 8; b++) {
        const float4* sb = sbuf + b * 256;
        float4 c0 = sb[lane], c1 = sb[lane + 64], c2 = sb[lane + 128], c3 = sb[lane + 192];
        float a = wv0.x*c0.x + wv0.y*c0.y + wv0.z*c0.z + wv0.w*c0.w
                + wv1.x*c1.x + wv1.y*c1.y + wv1.z*c1.z + wv1.w*c1.w
                + wv2.x*c2.x + wv2.y*c2.y + wv2.z*c2.z + wv2.w*c2.w
                + wv3.x*c3.x + wv3.y*c3.y + wv3.z*c3.z + wv3.w*c3.w;
        a = wave_sum(a);
        if (lane == 0) ws[OFF_PV + b * NC + o] = a;
      }
    }
  }
}

// ---------------- K4: pass over x: combine kq partials, GN stats + score dots ----------------
// grid (lc=4, cs=2, b*g=64), block 256. Each block: 64 channels x 1024 float4 l's.
__global__ void k_pass1(const float* __restrict__ x, const float* __restrict__ gng,
                        float* __restrict__ ws) {
  __shared__ float red[256];
  __shared__ float sw[64];
  int t  = threadIdx.x;
  int lc = blockIdx.x;          // 0..3
  int cs = blockIdx.y;          // 0..1
  int bz = blockIdx.z;          // b*8+g
  int b = bz >> 3, g = bz & 7;
  int c0 = g * 128 + cs * 64;
  if (t < 64) {                 // combine 64 kq partial chunks -> wcoef
    int c = c0 + t;
    const float* qp = ws + OFF_QP + b * 1024 + c;
    float s = 0.f;
    #pragma unroll 8
    for (int oc = 0; oc < 64; oc++) s += qp[(size_t)oc * 8192];
    sw[t] = gng[c] * s;
  }
  __syncthreads();
  int l4 = lc * 256 + t;
  const float4* x4 = reinterpret_cast<const float4*>(x);
  float4 tacc = make_float4(0.f, 0.f, 0.f, 0.f);
  float s1 = 0.f, s2 = 0.f;
  #pragma unroll 4
  for (int ci = 0; ci < 64; ci++) {
    float w = sw[ci];
    float4 v = x4[(size_t)(b * NC + c0 + ci) * 1024 + l4];
    tacc.x = fmaf(w, v.x, tacc.x);
    tacc.y = fmaf(w, v.y, tacc.y);
    tacc.z = fmaf(w, v.z, tacc.z);
    tacc.w = fmaf(w, v.w, tacc.w);
    s1 += (v.x + v.y) + (v.z + v.w);
    s2 = fmaf(v.x, v.x, s2); s2 = fmaf(v.y, v.y, s2);
    s2 = fmaf(v.z, v.z, s2); s2 = fmaf(v.w, v.w, s2);
  }
  float4* tp4 = reinterpret_cast<float4*>(ws + OFF_TPART) + (size_t)(bz * 2 + cs) * 1024;
  tp4[l4] = tacc;
  float S1 = breduce_sum(s1, red);
  float S2 = breduce_sum(s2, red);
  if (t == 0) {
    float* sp = ws + OFF_SPART + (bz * 8 + cs * 4 + lc) * 2;
    sp[0] = S1; sp[1] = S2;
  }
}

// ---------------- K5: per-b combine + softmax -> attn ----------------
__global__ void k_softmax(float* __restrict__ ws) {
  __shared__ float red[256];
  __shared__ float srstd[NG];
  int b = blockIdx.x, t = threadIdx.x;
  if (t < NG) {
    const float* sp = ws + OFF_SPART + (b * NG + t) * 16;
    float S1 = 0.f, S2 = 0.f;
    #pragma unroll
    for (int i = 0; i < 8; i++) { S1 += sp[i * 2]; S2 += sp[i * 2 + 1]; }
    const float invN = 1.0f / (128.0f * (float)NL);
    float mu = S1 * invN;
    float var = S2 * invN - mu * mu;
    srstd[t] = rsqrtf(var + EPSV);
  }
  __syncthreads();
  float sv[16];
  const float* tp = ws + OFF_TPART + (size_t)b * NG * 2 * NL;
  #pragma unroll
  for (int i = 0; i < 16; i++) {
    int l = t + i * 256;
    float acc = 0.f;
    #pragma unroll
    for (int g = 0; g < NG; g++) {
      const float* tg = tp + (size_t)g * 2 * NL;
      acc = fmaf(srstd[g], tg[l] + tg[NL + l], acc);
    }
    sv[i] = SCALEV * acc;   // per-b additive constants cancel under softmax
  }
  float m = sv[0];
  #pragma unroll
  for (int i = 1; i < 16; i++) m = fmaxf(m, sv[i]);
  float M = breduce_max(m, red);
  float s = 0.f;
  #pragma unroll
  for (int i = 0; i < 16; i++) { sv[i] = expf(sv[i] - M); s += sv[i]; }
  float S = breduce_sum(s, red);
  float inv = 1.0f / S;
  float* at = ws + OFF_ATTN + b * NL;
  #pragma unroll
  for (int i = 0; i < 16; i++) at[t + i * 256] = sv[i] * inv;
}

// ---------------- K6: out = x + attn*pv + bp ----------------
__global__ void k_out(const float* __restrict__ x, const float* __restrict__ bp,
                      const float* __restrict__ ws, float* __restrict__ out) {
  const float4* x4 = reinterpret_cast<const float4*>(x);
  float4* o4 = reinterpret_cast<float4*>(out);
  const float4* a4 = reinterpret_cast<const float4*>(ws + OFF_ATTN);
  const float* pv = ws + OFF_PV;
  const size_t NT4 = (size_t)NB * NC * NL / 4;  // 8388608
  for (size_t i = (size_t)blockIdx.x * blockDim.x + threadIdx.x; i < NT4;
       i += (size_t)gridDim.x * blockDim.x) {
    int b  = (int)(i >> 20);
    int c  = (int)((i >> 10) & (NC - 1));
    int l4 = (int)(i & 1023);
    float4 xv = x4[i];
    float4 av = a4[(size_t)b * 1024 + l4];
    float p  = pv[b * NC + c];
    float bb = bp[c];
    float4 r;
    r.x = xv.x + fmaf(av.x, p, bb);
    r.y = xv.y + fmaf(av.y, p, bb);
    r.z = xv.z + fmaf(av.z, p, bb);
    r.w = xv.w + fmaf(av.w, p, bb);
    o4[i] = r;
  }
}

extern "C" void kernel_launch(void* const* d_in, const int* in_sizes, int n_in,
                              void* d_out, int out_size, void* d_ws, size_t ws_size,
                              hipStream_t stream) {
  const float* x    = (const float*)d_in[0];
  const float* ctx  = (const float*)d_in[1];
  const float* gng  = (const float*)d_in[2];
  // d_in[3] = gn_beta, d_in[7] = bq : per-b constants, cancel under softmax
  const float* lng  = (const float*)d_in[4];
  const float* lnb  = (const float*)d_in[5];
  const float* Wq   = (const float*)d_in[6];
  const float* Wkv  = (const float*)d_in[8];
  const float* bkv  = (const float*)d_in[9];
  const float* Wp   = (const float*)d_in[10];
  const float* bp   = (const float*)d_in[11];
  float* ws  = (float*)d_ws;
  float* out = (float*)d_out;

  hipLaunchKernelGGL(k_ln,      dim3(NB),        dim3(256), 0, stream, ctx, lng, lnb, ws);
  hipLaunchKernelGGL(k_kv,      dim3(128),       dim3(256), 0, stream, Wkv, bkv, ws);
  hipLaunchKernelGGL(k_mv,      dim3(128),       dim3(256), 0, stream, Wq, Wp, ws);
  hipLaunchKernelGGL(k_pass1,   dim3(4, 2, 64),  dim3(256), 0, stream, x, gng, ws);
  hipLaunchKernelGGL(k_softmax, dim3(NB),        dim3(256), 0, stream, ws);
  hipLaunchKernelGGL(k_out,     dim3(2048),      dim3(256), 0, stream, x, bp, ws, out);
}

// Round 6
// 107.472 us; speedup vs baseline: 2.2530x; 1.3355x over previous
//
#include <hip/hip_runtime.h>
#include <math.h>

#define NB   8
#define NC   1024
#define NL   4096
#define NCTX 768
#define NG   8
#define EPSV 1e-5f
#define SCALEV 0.03125f   // 1024^-0.5

// workspace layout (float offsets)
enum : int {
  OFF_KV    = 0,                         // 8*2048   = 16384
  OFF_PV    = 16384,                     // 8*1024   = 8192
  OFF_QP    = 24576,                     // 64 oc * 8 b * 1024 c = 524288
  OFF_SPART = 548864,                    // 8b*8g*8*2 = 1024
  OFF_TPART = 549888,                    // 8b*8g*2cs*4096 = 524288
  OFF_ATTN  = 1074176,                   // 8*4096 = 32768
  OFF_S     = 1106944,                   // 8
  WS_FLOATS = 1106952                    // ~4.43 MB
};

__device__ __forceinline__ float breduce_sum(float v, float* red) {
  int t = threadIdx.x;
  red[t] = v; __syncthreads();
  for (int s = 128; s > 0; s >>= 1) { if (t < s) red[t] += red[t + s]; __syncthreads(); }
  float r = red[0]; __syncthreads();
  return r;
}
__device__ __forceinline__ float wave_sum(float v) {
  #pragma unroll
  for (int off = 32; off > 0; off >>= 1) v += __shfl_xor(v, off, 64);
  return v;
}

// ---------------- K1: LN(context) in-LDS + kv = ctxn @ Wkv^T + bkv ----------------
// grid 128, block 256 (4 waves): each wave LNs 2 batches, then 16 kv rows/block.
__global__ void k_kv(const float* __restrict__ ctx, const float* __restrict__ lng,
                     const float* __restrict__ lnb, const float* __restrict__ Wkv,
                     const float* __restrict__ bkv, float* __restrict__ ws) {
  __shared__ __align__(16) float scf[8 * NCTX];   // 24 KB
  int t = threadIdx.x, bid = blockIdx.x;
  int wave = t >> 6, lane = t & 63;
  if (bid == 0 && t < NB) ws[OFF_S + t] = 0.f;    // zero softmax sums for k_scores
  // LN: wave handles batches wave*2, wave*2+1
  #pragma unroll
  for (int bb = 0; bb < 2; bb++) {
    int b = wave * 2 + bb;
    const float* row = ctx + b * NCTX;
    float v[12];
    float s = 0.f;
    #pragma unroll
    for (int k = 0; k < 12; k++) { v[k] = row[lane + 64 * k]; s += v[k]; }
    float mu = wave_sum(s) * (1.0f / NCTX);
    float s2 = 0.f;
    #pragma unroll
    for (int k = 0; k < 12; k++) { float d = v[k] - mu; s2 = fmaf(d, d, s2); }
    float rstd = rsqrtf(wave_sum(s2) * (1.0f / NCTX) + EPSV);
    #pragma unroll
    for (int k = 0; k < 12; k++) {
      int j = lane + 64 * k;
      scf[b * NCTX + j] = (v[k] - mu) * rstd * lng[j] + lnb[j];
    }
  }
  __syncthreads();
  const float4* W4 = reinterpret_cast<const float4*>(Wkv);
  const float4* sc4 = reinterpret_cast<const float4*>(scf);
  #pragma unroll
  for (int rr = 0; rr < 4; rr++) {
    int j = bid * 16 + wave * 4 + rr;
    float4 wv0 = W4[(size_t)j * 192 + lane];
    float4 wv1 = W4[(size_t)j * 192 + lane + 64];
    float4 wv2 = W4[(size_t)j * 192 + lane + 128];
    #pragma unroll
    for (int b = 0; b < 8; b++) {
      const float4* sb = sc4 + b * 192;
      float4 c0 = sb[lane], c1 = sb[lane + 64], c2 = sb[lane + 128];
      float a = wv0.x*c0.x + wv0.y*c0.y + wv0.z*c0.z + wv0.w*c0.w
              + wv1.x*c1.x + wv1.y*c1.y + wv1.z*c1.z + wv1.w*c1.w
              + wv2.x*c2.x + wv2.y*c2.y + wv2.z*c2.z + wv2.w*c2.w;
      a = wave_sum(a);
      if (lane == 0) ws[OFF_KV + b * 2048 + j] = a + bkv[j];
    }
  }
}

// ---------------- K2: kq partials (split-K) + pv (wave-per-row) ----------------
__global__ void k_mv(const float* __restrict__ Wq, const float* __restrict__ Wp,
                     float* __restrict__ ws) {
  __shared__ float4 sbuf[8 * 256];      // 32 KB, dual-use
  int t = threadIdx.x, bid = blockIdx.x;
  if (bid < 64) {
    float* sk = reinterpret_cast<float*>(sbuf);   // sk[8][16]
    if (t < 128) { int b = t >> 4, o = t & 15; sk[b * 16 + o] = ws[OFF_KV + b * 2048 + bid * 16 + o]; }
    __syncthreads();
    const float4* Wq4 = reinterpret_cast<const float4*>(Wq);
    float4 acc[8];
    #pragma unroll
    for (int b = 0; b < 8; b++) acc[b] = make_float4(0.f, 0.f, 0.f, 0.f);
    int o0 = bid * 16;
    #pragma unroll 4
    for (int oi = 0; oi < 16; oi++) {
      float4 w = Wq4[(size_t)(o0 + oi) * 256 + t];
      #pragma unroll
      for (int b = 0; b < 8; b++) {
        float kk = sk[b * 16 + oi];
        acc[b].x = fmaf(kk, w.x, acc[b].x);
        acc[b].y = fmaf(kk, w.y, acc[b].y);
        acc[b].z = fmaf(kk, w.z, acc[b].z);
        acc[b].w = fmaf(kk, w.w, acc[b].w);
      }
    }
    float4* qp4 = reinterpret_cast<float4*>(ws + OFF_QP);
    #pragma unroll
    for (int b = 0; b < 8; b++) qp4[(bid * 8 + b) * 256 + t] = acc[b];
  } else {
    const float4* kv4 = reinterpret_cast<const float4*>(ws + OFF_KV);
    #pragma unroll
    for (int rep = 0; rep < 8; rep++) {
      int idx = rep * 256 + t;            // idx < 2048
      int b = idx >> 8, i = idx & 255;
      sbuf[idx] = kv4[b * 512 + 256 + i]; // v half
    }
    __syncthreads();
    int wave = t >> 6, lane = t & 63;
    const float4* Wp4 = reinterpret_cast<const float4*>(Wp);
    #pragma unroll
    for (int rr = 0; rr < 4; rr++) {
      int o = (bid - 64) * 16 + wave * 4 + rr;
      float4 wv0 = Wp4[(size_t)o * 256 + lane];
      float4 wv1 = Wp4[(size_t)o * 256 + lane + 64];
      float4 wv2 = Wp4[(size_t)o * 256 + lane + 128];
      float4 wv3 = Wp4[(size_t)o * 256 + lane + 192];
      #pragma unroll
      for (int b = 0; b < 8; b++) {
        const float4* sb = sbuf + b * 256;
        float4 c0 = sb[lane], c1 = sb[lane + 64], c2 = sb[lane + 128], c3 = sb[lane + 192];
        float a = wv0.x*c0.x + wv0.y*c0.y + wv0.z*c0.z + wv0.w*c0.w
                + wv1.x*c1.x + wv1.y*c1.y + wv1.z*c1.z + wv1.w*c1.w
                + wv2.x*c2.x + wv2.y*c2.y + wv2.z*c2.z + wv2.w*c2.w
                + wv3.x*c3.x + wv3.y*c3.y + wv3.z*c3.z + wv3.w*c3.w;
        a = wave_sum(a);
        if (lane == 0) ws[OFF_PV + b * NC + o] = a;
      }
    }
  }
}

// ---------------- K3: pass over x: combine kq partials, GN stats + score dots ----------------
// grid (lc=4, cs=2, b*g=64), block 256. Each block: 64 channels x 1024 float4 l's.
__global__ void k_pass1(const float* __restrict__ x, const float* __restrict__ gng,
                        float* __restrict__ ws) {
  __shared__ float red[256];
  __shared__ float sw[64];
  int t  = threadIdx.x;
  int lc = blockIdx.x;          // 0..3
  int cs = blockIdx.y;          // 0..1
  int bz = blockIdx.z;          // b*8+g
  int b = bz >> 3, g = bz & 7;
  int c0 = g * 128 + cs * 64;
  // combine 64 kq partial chunks -> wcoef (all 256 threads: 64 c x 4 oc-splits)
  {
    int c_l = t & 63, sp = t >> 6;
    const float* qp = ws + OFF_QP + b * 1024 + c0 + c_l;
    float s = 0.f;
    #pragma unroll 4
    for (int oc = sp * 16; oc < sp * 16 + 16; oc++) s += qp[(size_t)oc * 8192];
    red[t] = s;
    __syncthreads();
    if (t < 64) sw[t] = gng[c0 + t] * ((red[t] + red[t + 64]) + (red[t + 128] + red[t + 192]));
    __syncthreads();
  }
  int l4 = lc * 256 + t;
  const float4* x4 = reinterpret_cast<const float4*>(x);
  float4 tacc = make_float4(0.f, 0.f, 0.f, 0.f);
  float s1 = 0.f, s2 = 0.f;
  #pragma unroll 4
  for (int ci = 0; ci < 64; ci++) {
    float w = sw[ci];
    float4 v = x4[(size_t)(b * NC + c0 + ci) * 1024 + l4];
    tacc.x = fmaf(w, v.x, tacc.x);
    tacc.y = fmaf(w, v.y, tacc.y);
    tacc.z = fmaf(w, v.z, tacc.z);
    tacc.w = fmaf(w, v.w, tacc.w);
    s1 += (v.x + v.y) + (v.z + v.w);
    s2 = fmaf(v.x, v.x, s2); s2 = fmaf(v.y, v.y, s2);
    s2 = fmaf(v.z, v.z, s2); s2 = fmaf(v.w, v.w, s2);
  }
  float4* tp4 = reinterpret_cast<float4*>(ws + OFF_TPART) + (size_t)(bz * 2 + cs) * 1024;
  tp4[l4] = tacc;
  float S1 = breduce_sum(s1, red);
  float S2 = breduce_sum(s2, red);
  if (t == 0) {
    float* sp = ws + OFF_SPART + (bz * 8 + cs * 4 + lc) * 2;
    sp[0] = S1; sp[1] = S2;
  }
}

// ---------------- K4: scores -> exp (no global max needed; scores bounded) ----------------
// grid (lc=8, b=8), block 256: each block 512 l's. Writes e=exp(s) to ATTN, atomicAdds sum.
__global__ void k_scores(float* __restrict__ ws) {
  __shared__ float srstd[NG];
  __shared__ float red[256];
  int t = threadIdx.x, lc = blockIdx.x, b = blockIdx.y;
  if (t < NG) {
    const float* sp = ws + OFF_SPART + (b * 8 + t) * 16;
    float S1 = 0.f, S2 = 0.f;
    #pragma unroll
    for (int i = 0; i < 8; i++) { S1 += sp[i * 2]; S2 += sp[i * 2 + 1]; }
    const float invN = 1.0f / (128.0f * (float)NL);
    float mu = S1 * invN;
    float var = S2 * invN - mu * mu;
    srstd[t] = rsqrtf(var + EPSV);
  }
  __syncthreads();
  float esum = 0.f;
  #pragma unroll
  for (int r = 0; r < 2; r++) {
    int l = lc * 512 + r * 256 + t;
    float acc = 0.f;
    #pragma unroll
    for (int g = 0; g < NG; g++) {
      const float* tg = ws + OFF_TPART + (size_t)((b * 8 + g) * 2) * NL;
      acc = fmaf(srstd[g], tg[l] + tg[NL + l], acc);
    }
    float e = expf(fminf(SCALEV * acc, 60.0f));
    ws[OFF_ATTN + b * NL + l] = e;
    esum += e;
  }
  float tot = breduce_sum(esum, red);
  if (t == 0) atomicAdd(ws + OFF_S + b, tot);
}

// ---------------- K5: out = x + e*(pv/S) + bp ----------------
__global__ void k_out(const float* __restrict__ x, const float* __restrict__ bp,
                      const float* __restrict__ ws, float* __restrict__ out) {
  const float4* x4 = reinterpret_cast<const float4*>(x);
  float4* o4 = reinterpret_cast<float4*>(out);
  const float4* a4 = reinterpret_cast<const float4*>(ws + OFF_ATTN);
  const float* pv = ws + OFF_PV;
  const float* Ss = ws + OFF_S;
  const size_t NT4 = (size_t)NB * NC * NL / 4;  // 8388608
  for (size_t i = (size_t)blockIdx.x * blockDim.x + threadIdx.x; i < NT4;
       i += (size_t)gridDim.x * blockDim.x) {
    int b  = (int)(i >> 20);
    int c  = (int)((i >> 10) & (NC - 1));
    int l4 = (int)(i & 1023);
    float4 xv = x4[i];
    float4 av = a4[(size_t)b * 1024 + l4];
    float p  = pv[b * NC + c] / Ss[b];
    float bb = bp[c];
    float4 r;
    r.x = xv.x + fmaf(av.x, p, bb);
    r.y = xv.y + fmaf(av.y, p, bb);
    r.z = xv.z + fmaf(av.z, p, bb);
    r.w = xv.w + fmaf(av.w, p, bb);
    o4[i] = r;
  }
}

extern "C" void kernel_launch(void* const* d_in, const int* in_sizes, int n_in,
                              void* d_out, int out_size, void* d_ws, size_t ws_size,
                              hipStream_t stream) {
  const float* x    = (const float*)d_in[0];
  const float* ctx  = (const float*)d_in[1];
  const float* gng  = (const float*)d_in[2];
  // d_in[3] = gn_beta, d_in[7] = bq : per-b constants, cancel under softmax
  const float* lng  = (const float*)d_in[4];
  const float* lnb  = (const float*)d_in[5];
  const float* Wq   = (const float*)d_in[6];
  const float* Wkv  = (const float*)d_in[8];
  const float* bkv  = (const float*)d_in[9];
  const float* Wp   = (const float*)d_in[10];
  const float* bp   = (const float*)d_in[11];
  float* ws  = (float*)d_ws;
  float* out = (float*)d_out;

  hipLaunchKernelGGL(k_kv,     dim3(128),       dim3(256), 0, stream, ctx, lng, lnb, Wkv, bkv, ws);
  hipLaunchKernelGGL(k_mv,     dim3(128),       dim3(256), 0, stream, Wq, Wp, ws);
  hipLaunchKernelGGL(k_pass1,  dim3(4, 2, 64),  dim3(256), 0, stream, x, gng, ws);
  hipLaunchKernelGGL(k_scores, dim3(8, 8),      dim3(256), 0, stream, ws);
  hipLaunchKernelGGL(k_out,    dim3(2048),      dim3(256), 0, stream, x, bp, ws, out);
}

// Round 8
// 106.508 us; speedup vs baseline: 2.2733x; 1.0090x over previous
//
#include <hip/hip_runtime.h>
#include <math.h>

#define NB   8
#define NC   1024
#define NL   4096
#define NCTX 768
#define EPSV 1e-5f
#define SCALEV 0.03125f   // 1024^-0.5

// workspace layout (float offsets)
enum : int {
  OFF_KV    = 0,         // 8*2048 = 16384
  OFF_PV    = 16384,     // 8*1024 = 8192
  OFF_QP    = 24576,     // 64 oc * 8 b * 1024 c = 524288
  OFF_SPART = 548864,    // 64 bz * 32 * 2 = 4096
  OFF_TPART = 552960,    // 64 bz * 2 cs * 4096 = 524288
  OFF_ATTN  = 1077248,   // 8*4096 = 32768
  OFF_S     = 1110016,   // 8
  WS_FLOATS = 1110024    // ~4.44 MB
};

__device__ __forceinline__ float breduce_sum(float v, float* red) {
  int t = threadIdx.x;
  red[t] = v; __syncthreads();
  for (int s = 128; s > 0; s >>= 1) { if (t < s) red[t] += red[t + s]; __syncthreads(); }
  float r = red[0]; __syncthreads();
  return r;
}
__device__ __forceinline__ float wave_sum(float v) {
  #pragma unroll
  for (int off = 32; off > 0; off >>= 1) v += __shfl_xor(v, off, 64);
  return v;
}

// ---------------- K1: LN(context) in-LDS + kv = ctxn @ Wkv^T + bkv ----------------
// grid 128, block 256 (4 waves): each wave LNs 2 batches, then 16 kv rows/block.
__global__ void k_kv(const float* __restrict__ ctx, const float* __restrict__ lng,
                     const float* __restrict__ lnb, const float* __restrict__ Wkv,
                     const float* __restrict__ bkv, float* __restrict__ ws) {
  __shared__ __align__(16) float scf[8 * NCTX];   // 24 KB
  int t = threadIdx.x, bid = blockIdx.x;
  int wave = t >> 6, lane = t & 63;
  if (bid == 0 && t < NB) ws[OFF_S + t] = 0.f;    // zero softmax sums for k_scores
  #pragma unroll
  for (int bb = 0; bb < 2; bb++) {
    int b = wave * 2 + bb;
    const float* row = ctx + b * NCTX;
    float v[12];
    float s = 0.f;
    #pragma unroll
    for (int k = 0; k < 12; k++) { v[k] = row[lane + 64 * k]; s += v[k]; }
    float mu = wave_sum(s) * (1.0f / NCTX);
    float s2 = 0.f;
    #pragma unroll
    for (int k = 0; k < 12; k++) { float d = v[k] - mu; s2 = fmaf(d, d, s2); }
    float rstd = rsqrtf(wave_sum(s2) * (1.0f / NCTX) + EPSV);
    #pragma unroll
    for (int k = 0; k < 12; k++) {
      int j = lane + 64 * k;
      scf[b * NCTX + j] = (v[k] - mu) * rstd * lng[j] + lnb[j];
    }
  }
  __syncthreads();
  const float4* W4 = reinterpret_cast<const float4*>(Wkv);
  const float4* sc4 = reinterpret_cast<const float4*>(scf);
  #pragma unroll
  for (int rr = 0; rr < 4; rr++) {
    int j = bid * 16 + wave * 4 + rr;
    float4 wv0 = W4[(size_t)j * 192 + lane];
    float4 wv1 = W4[(size_t)j * 192 + lane + 64];
    float4 wv2 = W4[(size_t)j * 192 + lane + 128];
    #pragma unroll
    for (int b = 0; b < 8; b++) {
      const float4* sb = sc4 + b * 192;
      float4 c0 = sb[lane], c1 = sb[lane + 64], c2 = sb[lane + 128];
      float a = wv0.x*c0.x + wv0.y*c0.y + wv0.z*c0.z + wv0.w*c0.w
              + wv1.x*c1.x + wv1.y*c1.y + wv1.z*c1.z + wv1.w*c1.w
              + wv2.x*c2.x + wv2.y*c2.y + wv2.z*c2.z + wv2.w*c2.w;
      a = wave_sum(a);
      if (lane == 0) ws[OFF_KV + b * 2048 + j] = a + bkv[j];
    }
  }
}

// ---------------- K2: kq partials (split-K) + pv (wave-per-row) ----------------
__global__ void k_mv(const float* __restrict__ Wq, const float* __restrict__ Wp,
                     float* __restrict__ ws) {
  __shared__ float4 sbuf[8 * 256];      // 32 KB, dual-use
  int t = threadIdx.x, bid = blockIdx.x;
  if (bid < 64) {
    float* sk = reinterpret_cast<float*>(sbuf);   // sk[8][16]
    if (t < 128) { int b = t >> 4, o = t & 15; sk[b * 16 + o] = ws[OFF_KV + b * 2048 + bid * 16 + o]; }
    __syncthreads();
    const float4* Wq4 = reinterpret_cast<const float4*>(Wq);
    float4 acc[8];
    #pragma unroll
    for (int b = 0; b < 8; b++) acc[b] = make_float4(0.f, 0.f, 0.f, 0.f);
    int o0 = bid * 16;
    #pragma unroll 4
    for (int oi = 0; oi < 16; oi++) {
      float4 w = Wq4[(size_t)(o0 + oi) * 256 + t];
      #pragma unroll
      for (int b = 0; b < 8; b++) {
        float kk = sk[b * 16 + oi];
        acc[b].x = fmaf(kk, w.x, acc[b].x);
        acc[b].y = fmaf(kk, w.y, acc[b].y);
        acc[b].z = fmaf(kk, w.z, acc[b].z);
        acc[b].w = fmaf(kk, w.w, acc[b].w);
      }
    }
    float4* qp4 = reinterpret_cast<float4*>(ws + OFF_QP);
    #pragma unroll
    for (int b = 0; b < 8; b++) qp4[(bid * 8 + b) * 256 + t] = acc[b];
  } else {
    const float4* kv4 = reinterpret_cast<const float4*>(ws + OFF_KV);
    #pragma unroll
    for (int rep = 0; rep < 8; rep++) {
      int idx = rep * 256 + t;            // idx < 2048
      int b = idx >> 8, i = idx & 255;
      sbuf[idx] = kv4[b * 512 + 256 + i]; // v half
    }
    __syncthreads();
    int wave = t >> 6, lane = t & 63;
    const float4* Wp4 = reinterpret_cast<const float4*>(Wp);
    #pragma unroll
    for (int rr = 0; rr < 4; rr++) {
      int o = (bid - 64) * 16 + wave * 4 + rr;
      float4 wv0 = Wp4[(size_t)o * 256 + lane];
      float4 wv1 = Wp4[(size_t)o * 256 + lane + 64];
      float4 wv2 = Wp4[(size_t)o * 256 + lane + 128];
      float4 wv3 = Wp4[(size_t)o * 256 + lane + 192];
      #pragma unroll
      for (int b = 0; b < 8; b++) {
        const float4* sb = sbuf + b * 256;
        float4 c0 = sb[lane], c1 = sb[lane + 64], c2 = sb[lane + 128], c3 = sb[lane + 192];
        float a = wv0.x*c0.x + wv0.y*c0.y + wv0.z*c0.z + wv0.w*c0.w
                + wv1.x*c1.x + wv1.y*c1.y + wv1.z*c1.z + wv1.w*c1.w
                + wv2.x*c2.x + wv2.y*c2.y + wv2.z*c2.z + wv2.w*c2.w
                + wv3.x*c3.x + wv3.y*c3.y + wv3.z*c3.z + wv3.w*c3.w;
        a = wave_sum(a);
        if (lane == 0) ws[OFF_PV + b * NC + o] = a;
      }
    }
  }
}

// ---------------- K3: stream x — GN stats + score partial dots ----------------
// grid (lc=16, cs=2, bz=64), block 256: 2048 blocks, 32 waves/CU.
// Each block: 64 channels x 64 float4 l's; 4-way channel split per thread-quarter.
__global__ void k_pass1(const float* __restrict__ x, const float* __restrict__ gng,
                        float* __restrict__ ws) {
  __shared__ float red[256];
  __shared__ float sw[64];
  __shared__ __align__(16) float4 part[192];
  int t  = threadIdx.x;
  int lc = blockIdx.x;          // 0..15
  int cs = blockIdx.y;          // 0..1
  int bz = blockIdx.z;          // b*8+g
  int b = bz >> 3, g = bz & 7;
  int c0 = g * 128 + cs * 64;
  // combine 64 kq o-chunk partials -> wcoef for our 64 channels
  {
    int cl = t & 63, sp = t >> 6;
    const float* qp = ws + OFF_QP + b * 1024 + c0 + cl;
    float s = 0.f;
    #pragma unroll 4
    for (int oc = sp * 16; oc < sp * 16 + 16; oc++) s += qp[(size_t)oc * 8192];
    red[t] = s;
    __syncthreads();
    if (t < 64) sw[t] = gng[c0 + t] * ((red[t] + red[t + 64]) + (red[t + 128] + red[t + 192]));
    __syncthreads();
  }
  int tl = t & 63, q = t >> 6;
  int l4 = lc * 64 + tl;
  const float4* x4 = reinterpret_cast<const float4*>(x);
  float4 tacc = make_float4(0.f, 0.f, 0.f, 0.f);
  float s1 = 0.f, s2 = 0.f;
  #pragma unroll 4
  for (int ci = q * 16; ci < q * 16 + 16; ci++) {
    float w = sw[ci];
    float4 v = x4[(size_t)(b * NC + c0 + ci) * 1024 + l4];
    tacc.x = fmaf(w, v.x, tacc.x);
    tacc.y = fmaf(w, v.y, tacc.y);
    tacc.z = fmaf(w, v.z, tacc.z);
    tacc.w = fmaf(w, v.w, tacc.w);
    s1 += (v.x + v.y) + (v.z + v.w);
    s2 = fmaf(v.x, v.x, s2); s2 = fmaf(v.y, v.y, s2);
    s2 = fmaf(v.z, v.z, s2); s2 = fmaf(v.w, v.w, s2);
  }
  if (q > 0) part[(q - 1) * 64 + tl] = tacc;
  __syncthreads();
  if (q == 0) {
    float4 p0 = part[tl], p1 = part[64 + tl], p2 = part[128 + tl];
    tacc.x += (p0.x + p1.x) + p2.x;
    tacc.y += (p0.y + p1.y) + p2.y;
    tacc.z += (p0.z + p1.z) + p2.z;
    tacc.w += (p0.w + p1.w) + p2.w;
    reinterpret_cast<float4*>(ws + OFF_TPART)[(size_t)(bz * 2 + cs) * 1024 + l4] = tacc;
  }
  float S1 = breduce_sum(s1, red);
  float S2 = breduce_sum(s2, red);
  if (t == 0) {
    float* sp = ws + OFF_SPART + (bz * 32 + cs * 16 + lc) * 2;
    sp[0] = S1; sp[1] = S2;
  }
}

// ---------------- K4: scores -> exp (no global max; scores bounded) ----------------
// grid (lc=8, b=8), block 256: 512 l's per block. Writes e=exp(s), atomicAdds sum.
__global__ void k_scores(float* __restrict__ ws) {
  __shared__ float srstd[8];
  __shared__ float red[256];
  int t = threadIdx.x, lc = blockIdx.x, b = blockIdx.y;
  if (t < 8) {
    const float* sp = ws + OFF_SPART + (b * 8 + t) * 64;
    float S1 = 0.f, S2 = 0.f;
    #pragma unroll
    for (int i = 0; i < 32; i++) { S1 += sp[i * 2]; S2 += sp[i * 2 + 1]; }
    const float invN = 1.0f / (128.0f * (float)NL);
    float mu = S1 * invN;
    float var = S2 * invN - mu * mu;
    srstd[t] = rsqrtf(var + EPSV);
  }
  __syncthreads();
  float esum = 0.f;
  #pragma unroll
  for (int r = 0; r < 2; r++) {
    int l = lc * 512 + r * 256 + t;
    float acc = 0.f;
    #pragma unroll
    for (int g = 0; g < 8; g++) {
      const float* tg = ws + OFF_TPART + (size_t)(b * 8 + g) * 8192;
      acc = fmaf(srstd[g], tg[l] + tg[4096 + l], acc);
    }
    float e = expf(fminf(SCALEV * acc, 60.0f));  // per-b consts cancel under softmax
    ws[OFF_ATTN + b * NL + l] = e;
    esum += e;
  }
  float tot = breduce_sum(esum, red);
  if (t == 0) atomicAdd(ws + OFF_S + b, tot);
}

// ---------------- K5: out = x + e*(pv/S) + bp ----------------
__global__ void k_out(const float* __restrict__ x, const float* __restrict__ bp,
                      const float* __restrict__ ws, float* __restrict__ out) {
  const float4* x4 = reinterpret_cast<const float4*>(x);
  float4* o4 = reinterpret_cast<float4*>(out);
  const float4* a4 = reinterpret_cast<const float4*>(ws + OFF_ATTN);
  const float* pv = ws + OFF_PV;
  const float* Ss = ws + OFF_S;
  const size_t NT4 = (size_t)NB * NC * NL / 4;  // 8388608
  for (size_t i = (size_t)blockIdx.x * blockDim.x + threadIdx.x; i < NT4;
       i += (size_t)gridDim.x * blockDim.x) {
    int b  = (int)(i >> 20);
    int c  = (int)((i >> 10) & (NC - 1));
    int l4 = (int)(i & 1023);
    float4 xv = x4[i];
    float4 av = a4[(size_t)b * 1024 + l4];
    float p  = pv[b * NC + c] / Ss[b];
    float bb = bp[c];
    float4 r;
    r.x = xv.x + fmaf(av.x, p, bb);
    r.y = xv.y + fmaf(av.y, p, bb);
    r.z = xv.z + fmaf(av.z, p, bb);
    r.w = xv.w + fmaf(av.w, p, bb);
    o4[i] = r;
  }
}

extern "C" void kernel_launch(void* const* d_in, const int* in_sizes, int n_in,
                              void* d_out, int out_size, void* d_ws, size_t ws_size,
                              hipStream_t stream) {
  const float* x    = (const float*)d_in[0];
  const float* ctx  = (const float*)d_in[1];
  const float* gng  = (const float*)d_in[2];
  // d_in[3] = gn_beta, d_in[7] = bq : per-b constants, cancel under softmax
  const float* lng  = (const float*)d_in[4];
  const float* lnb  = (const float*)d_in[5];
  const float* Wq   = (const float*)d_in[6];
  const float* Wkv  = (const float*)d_in[8];
  const float* bkv  = (const float*)d_in[9];
  const float* Wp   = (const float*)d_in[10];
  const float* bp   = (const float*)d_in[11];
  float* ws  = (float*)d_ws;
  float* out = (float*)d_out;

  hipLaunchKernelGGL(k_kv,     dim3(128),        dim3(256), 0, stream, ctx, lng, lnb, Wkv, bkv, ws);
  hipLaunchKernelGGL(k_mv,     dim3(128),        dim3(256), 0, stream, Wq, Wp, ws);
  hipLaunchKernelGGL(k_pass1,  dim3(16, 2, 64),  dim3(256), 0, stream, x, gng, ws);
  hipLaunchKernelGGL(k_scores, dim3(8, 8),       dim3(256), 0, stream, ws);
  hipLaunchKernelGGL(k_out,    dim3(2048),       dim3(256), 0, stream, x, bp, ws, out);
}